// Round 3
// baseline (658.941 us; speedup 1.0000x reference)
//
#include <hip/hip_runtime.h>
#include <hip/hip_bf16.h>
#include <math.h>

#define Bq 256
#define Tq 256
#define Hq 512
#define Eq 96

typedef __attribute__((ext_vector_type(8))) short short8;
typedef __attribute__((ext_vector_type(4))) float f32x4;

static __device__ __forceinline__ unsigned short f2bf(float f) {
  union { float f; unsigned u; } v; v.f = f;
  unsigned r = v.u + 0x7FFF + ((v.u >> 16) & 1);
  return (unsigned short)(r >> 16);
}

// saturating tanh: exp2 arg clamped so inf never appears
static __device__ __forceinline__ float sat_tanh(float x) {
  float ax = fminf(fabsf(x), 15.0f);
  float e = __builtin_exp2f(ax * 2.885390082f);  // 2*log2(e)
  float t = 1.0f - 2.0f / (e + 1.0f);
  return copysignf(t, x);
}

static __device__ __forceinline__ float sat_sig(float x) {
  float cx = fmaxf(fminf(x, 30.0f), -30.0f);
  return 1.0f / (1.0f + __builtin_exp2f(-cx * 1.442695041f));
}

// ---------------- K0: W_i2h fp32 [K][N] -> bf16 transposed [N][K] ----------
__global__ __launch_bounds__(256) void convW_k(const float* __restrict__ W,
                                               unsigned short* __restrict__ Wt) {
  __shared__ float tile[32][33];
  int bx = blockIdx.x & 15, by = blockIdx.x >> 4;
  int tx = threadIdx.x & 31, ty = threadIdx.x >> 5;  // 32 x 8
  #pragma unroll
  for (int i = 0; i < 32; i += 8)
    tile[ty + i][tx] = W[(size_t)(by * 32 + ty + i) * Hq + bx * 32 + tx];
  __syncthreads();
  #pragma unroll
  for (int i = 0; i < 32; i += 8)
    Wt[(size_t)(bx * 32 + ty + i) * Hq + by * 32 + tx] = f2bf(tile[tx][ty + i]);
}

// ---------------- K1: hp = prev_h @ W_h2h + b_h2h ---------------------------
#define BG 8
__global__ __launch_bounds__(256) void hproj_k(const float* __restrict__ ph,
                                               const float* __restrict__ Whh,
                                               const float* __restrict__ bh,
                                               float* __restrict__ hp) {
  __shared__ float xs[BG][Hq];
  int nc = blockIdx.x & 1;
  int bg = blockIdx.x >> 1;  // 0..31
  int tid = threadIdx.x;
  for (int i = tid; i < BG * Hq / 4; i += 256)
    ((float4*)&xs[0][0])[i] = ((const float4*)(ph + (size_t)bg * BG * Hq))[i];
  __syncthreads();
  int n = nc * 256 + tid;
  float acc[BG] = {0};
  #pragma unroll 4
  for (int d = 0; d < Hq; d++) {
    float w = Whh[(size_t)d * Hq + n];
    #pragma unroll
    for (int q = 0; q < BG; q++) acc[q] += xs[q][d] * w;
  }
  float bias = bh[n];
  #pragma unroll
  for (int q = 0; q < BG; q++) hp[(size_t)(bg * BG + q) * Hq + n] = acc[q] + bias;
}

// ---------------- K2: fused proj GEMM + tanh + w_score dot -> e ------------
#define BM 128
#define BN 128
#define BK 32
#define LDK 40  // shorts per LDS row: 32 + 8 pad

__global__ __launch_bounds__(256) void fused_score_k(
    const float* __restrict__ A,            // batch_H [65536, 512]
    const unsigned short* __restrict__ Wt,  // bf16 [N=512][K=512]
    const float* __restrict__ hp,           // [B, H]
    const float* __restrict__ wsc,          // [H]
    float* __restrict__ e) {                // [B*T], pre-zeroed
  __shared__ unsigned short As[BM * LDK];
  __shared__ unsigned short Bs[BN * LDK];
  __shared__ float hps[BN];
  __shared__ float wss[BN];

  const int tid = threadIdx.x;
  const int m0 = blockIdx.x * BM;
  const int n0 = blockIdx.y * BN;
  const int bb = m0 >> 8;  // batch idx, uniform per block (128 | 256)

  if (tid < BN) {
    hps[tid] = hp[(size_t)bb * Hq + n0 + tid];
    wss[tid] = wsc[n0 + tid];
  }

  const int wave = tid >> 6;
  const int lane = tid & 63;
  const int quad = lane >> 4;
  const int l16 = lane & 15;
  const int wm = (wave & 1) * 64;
  const int wn = (wave >> 1) * 64;

  f32x4 acc[4][4] = {};

  const int arow = tid >> 3;        // 0..31
  const int acol = (tid & 7) * 4;   // 0..28
  const int brow = tid >> 2;        // 0..63 (n), two passes of 64 rows
  const int bkh = (tid & 3) * 8;    // k offset in shorts: 0,8,16,24

  for (int k0 = 0; k0 < Hq; k0 += BK) {
    __syncthreads();
    // stage A: 128 rows x 32 k, fp32 -> bf16
    #pragma unroll
    for (int p = 0; p < 4; p++) {
      int r = arow + p * 32;
      const float4 v = *(const float4*)(&A[(size_t)(m0 + r) * Hq + k0 + acol]);
      ushort4 pk;
      pk.x = f2bf(v.x); pk.y = f2bf(v.y); pk.z = f2bf(v.z); pk.w = f2bf(v.w);
      *(ushort4*)&As[r * LDK + acol] = pk;
    }
    // stage B (already bf16-transposed): Bs[n][k]
    // uint4 = 8 shorts; 4 threads/row x 8 shorts = 32 shorts; 2 passes x 64 rows
    #pragma unroll
    for (int p = 0; p < 2; p++) {
      int r = brow + p * 64;
      const uint4 v = *(const uint4*)(&Wt[(size_t)(n0 + r) * Hq + k0 + bkh]);
      *(uint4*)&Bs[r * LDK + bkh] = v;
    }
    __syncthreads();

    short8 af[4], bfr[4];
    #pragma unroll
    for (int mi = 0; mi < 4; mi++)
      af[mi] = *(const short8*)&As[(wm + mi * 16 + l16) * LDK + quad * 8];
    #pragma unroll
    for (int ni = 0; ni < 4; ni++)
      bfr[ni] = *(const short8*)&Bs[(wn + ni * 16 + l16) * LDK + quad * 8];
    #pragma unroll
    for (int mi = 0; mi < 4; mi++)
      #pragma unroll
      for (int ni = 0; ni < 4; ni++)
        acc[mi][ni] = __builtin_amdgcn_mfma_f32_16x16x32_bf16(
            af[mi], bfr[ni], acc[mi][ni], 0, 0, 0);
  }

  // epilogue: e[m] += sum_n tanh(C[m,n] + hp[b,n]) * w_score[n]
  float hv[4], wv[4];
  #pragma unroll
  for (int ni = 0; ni < 4; ni++) {
    int c = wn + ni * 16 + l16;
    hv[ni] = hps[c];
    wv[ni] = wss[c];
  }
  #pragma unroll
  for (int mi = 0; mi < 4; mi++) {
    float s[4] = {0, 0, 0, 0};
    #pragma unroll
    for (int ni = 0; ni < 4; ni++)
      #pragma unroll
      for (int r = 0; r < 4; r++)
        s[r] += sat_tanh(acc[mi][ni][r] + hv[ni]) * wv[ni];
    #pragma unroll
    for (int r = 0; r < 4; r++) {
      s[r] += __shfl_xor(s[r], 8, 64);
      s[r] += __shfl_xor(s[r], 4, 64);
      s[r] += __shfl_xor(s[r], 2, 64);
      s[r] += __shfl_xor(s[r], 1, 64);
    }
    if (l16 == 0) {
      int row = m0 + wm + mi * 16 + quad * 4;
      #pragma unroll
      for (int r = 0; r < 4; r++) atomicAdd(&e[row + r], s[r]);
    }
  }
}

// ---------------- K3: softmax over T per batch, IN PLACE -------------------
// safe in place: all reads happen before sync1, all writes after sync2
__global__ __launch_bounds__(256) void softmax_k(float* __restrict__ ea) {
  __shared__ float red[8];
  int b = blockIdx.x, t = threadIdx.x;
  int wave = t >> 6, lane = t & 63;
  float x = ea[b * Tq + t];
  float m = x;
  #pragma unroll
  for (int off = 32; off >= 1; off >>= 1) m = fmaxf(m, __shfl_xor(m, off, 64));
  if (lane == 0) red[wave] = m;
  __syncthreads();
  m = fmaxf(fmaxf(red[0], red[1]), fmaxf(red[2], red[3]));
  float ex = __builtin_exp2f((x - m) * 1.442695041f);
  float s = ex;
  #pragma unroll
  for (int off = 32; off >= 1; off >>= 1) s += __shfl_xor(s, off, 64);
  if (lane == 0) red[4 + wave] = s;
  __syncthreads();
  s = red[4] + red[5] + red[6] + red[7];
  ea[b * Tq + t] = ex / s;
}

// ---------------- K4: context = alpha^T . batch_H --------------------------
__global__ __launch_bounds__(256) void context_k(const float* __restrict__ alpha,
                                                 const float* __restrict__ bH,
                                                 float* __restrict__ ctx) {
  __shared__ float al[Tq];
  int b = blockIdx.x, tid = threadIdx.x;
  al[tid] = alpha[b * Tq + tid];
  __syncthreads();
  const float2* Hp = (const float2*)(bH + (size_t)b * Tq * Hq);
  float ax = 0.f, ay = 0.f;
  #pragma unroll 4
  for (int t = 0; t < Tq; t++) {
    float a = al[t];
    float2 v = Hp[t * (Hq / 2) + tid];
    ax += a * v.x;
    ay += a * v.y;
  }
  float2 o; o.x = ax; o.y = ay;
  ((float2*)(ctx + (size_t)b * Hq))[tid] = o;
}

// ---------------- K5: z = [ctx|onehot|prev_h] @ [W_lstm;U_lstm] + b,
//                   fused with LSTM gates -> h_new, c_new -------------------
#define ZBG 4
__global__ __launch_bounds__(256) void zgates_k(
    const float* __restrict__ ctx, const float* __restrict__ oneh,
    const float* __restrict__ ph, const float* __restrict__ pc,
    const float* __restrict__ Wl, const float* __restrict__ Ul,
    const float* __restrict__ bl,
    float* __restrict__ outh, float* __restrict__ outc) {
  __shared__ float xs[ZBG][1120];
  int hc = blockIdx.x & 1;   // h half (256 cols each)
  int bg = blockIdx.x >> 1;  // 0..63, 4 rows each
  int tid = threadIdx.x;
  for (int i = tid; i < ZBG * Hq; i += 256) {
    int q = i >> 9, d = i & 511;
    xs[q][d] = ctx[(size_t)(bg * ZBG + q) * Hq + d];
    xs[q][608 + d] = ph[(size_t)(bg * ZBG + q) * Hq + d];
  }
  for (int i = tid; i < ZBG * Eq; i += 256) {
    int q = i / Eq, d = i % Eq;
    xs[q][512 + d] = oneh[(bg * ZBG + q) * Eq + d];
  }
  __syncthreads();
  int h = hc * 256 + tid;  // 0..511
  float ai[ZBG] = {0}, af[ZBG] = {0}, ag[ZBG] = {0}, ao[ZBG] = {0};
  #pragma unroll 2
  for (int d = 0; d < 608; d++) {
    const float* wr = Wl + (size_t)d * 2048 + h;
    float wi = wr[0], wf = wr[512], wg = wr[1024], wo = wr[1536];
    #pragma unroll
    for (int q = 0; q < ZBG; q++) {
      float x = xs[q][d];
      ai[q] += x * wi; af[q] += x * wf; ag[q] += x * wg; ao[q] += x * wo;
    }
  }
  #pragma unroll 2
  for (int d = 0; d < 512; d++) {
    const float* wr = Ul + (size_t)d * 2048 + h;
    float wi = wr[0], wf = wr[512], wg = wr[1024], wo = wr[1536];
    #pragma unroll
    for (int q = 0; q < ZBG; q++) {
      float x = xs[q][608 + d];
      ai[q] += x * wi; af[q] += x * wf; ag[q] += x * wg; ao[q] += x * wo;
    }
  }
  float bi = bl[h], bf_ = bl[512 + h], bg_ = bl[1024 + h], bo = bl[1536 + h];
  #pragma unroll
  for (int q = 0; q < ZBG; q++) {
    int row = bg * ZBG + q;
    float cn = sat_sig(af[q] + bf_) * pc[(size_t)row * Hq + h] +
               sat_sig(ai[q] + bi) * sat_tanh(ag[q] + bg_);
    float hn = sat_sig(ao[q] + bo) * sat_tanh(cn);
    outh[(size_t)row * Hq + h] = hn;
    outc[(size_t)row * Hq + h] = cn;
  }
}

extern "C" void kernel_launch(void* const* d_in, const int* in_sizes, int n_in,
                              void* d_out, int out_size, void* d_ws, size_t ws_size,
                              hipStream_t stream) {
  const float* prev_h = (const float*)d_in[0];
  const float* prev_c = (const float*)d_in[1];
  const float* batch_H = (const float*)d_in[2];
  const float* oneh = (const float*)d_in[3];
  const float* W_i2h = (const float*)d_in[4];
  const float* W_h2h = (const float*)d_in[5];
  const float* b_h2h = (const float*)d_in[6];
  const float* w_score = (const float*)d_in[7];
  const float* W_lstm = (const float*)d_in[8];
  const float* U_lstm = (const float*)d_in[9];
  const float* b_lstm = (const float*)d_in[10];

  float* out = (float*)d_out;
  float* outh = out;                 // [B,H]
  float* outc = out + Bq * Hq;       // [B,H]
  float* alpha = out + 2 * Bq * Hq;  // [B,T] — doubles as e scratch

  // ws layout (1.0 MB total): [hp | later overlaid by ctx][Wt bf16]
  float* ws = (float*)d_ws;
  float* hp = ws;                                        // 131072 f
  float* ctx = ws;                                       // overlays hp (hp dead after K2)
  unsigned short* Wt = (unsigned short*)(ws + 131072);   // 262144 shorts = 512 KB

  hipMemsetAsync(alpha, 0, Bq * Tq * sizeof(float), stream);
  convW_k<<<256, 256, 0, stream>>>(W_i2h, Wt);
  hproj_k<<<64, 256, 0, stream>>>(prev_h, W_h2h, b_h2h, hp);
  dim3 g2(512, 4);
  fused_score_k<<<g2, 256, 0, stream>>>(batch_H, Wt, hp, w_score, alpha);
  softmax_k<<<256, 256, 0, stream>>>(alpha);
  context_k<<<256, 256, 0, stream>>>(alpha, batch_H, ctx);
  zgates_k<<<128, 256, 0, stream>>>(ctx, oneh, prev_h, prev_c,
                                    W_lstm, U_lstm, b_lstm, outh, outc);
}

// Round 4
// 485.992 us; speedup vs baseline: 1.3559x; 1.3559x over previous
//
#include <hip/hip_runtime.h>
#include <hip/hip_bf16.h>
#include <math.h>

#define Bq 256
#define Tq 256
#define Hq 512
#define Eq 96

typedef __attribute__((ext_vector_type(8))) short short8;
typedef __attribute__((ext_vector_type(4))) float f32x4;

static __device__ __forceinline__ unsigned short f2bf(float f) {
  union { float f; unsigned u; } v; v.f = f;
  unsigned r = v.u + 0x7FFF + ((v.u >> 16) & 1);
  return (unsigned short)(r >> 16);
}

// saturating tanh: exp2 arg clamped so inf never appears
static __device__ __forceinline__ float sat_tanh(float x) {
  float ax = fminf(fabsf(x), 15.0f);
  float e = __builtin_exp2f(ax * 2.885390082f);  // 2*log2(e)
  float t = 1.0f - 2.0f / (e + 1.0f);
  return copysignf(t, x);
}

static __device__ __forceinline__ float sat_sig(float x) {
  float cx = fmaxf(fminf(x, 30.0f), -30.0f);
  return 1.0f / (1.0f + __builtin_exp2f(-cx * 1.442695041f));
}

// ---------------- K0: W_i2h fp32 [K][N] -> bf16 transposed [N][K] ----------
__global__ __launch_bounds__(256) void convW_k(const float* __restrict__ W,
                                               unsigned short* __restrict__ Wt) {
  __shared__ float tile[32][33];
  int bx = blockIdx.x & 15, by = blockIdx.x >> 4;
  int tx = threadIdx.x & 31, ty = threadIdx.x >> 5;  // 32 x 8
  #pragma unroll
  for (int i = 0; i < 32; i += 8)
    tile[ty + i][tx] = W[(size_t)(by * 32 + ty + i) * Hq + bx * 32 + tx];
  __syncthreads();
  #pragma unroll
  for (int i = 0; i < 32; i += 8)
    Wt[(size_t)(bx * 32 + ty + i) * Hq + by * 32 + tx] = f2bf(tile[tx][ty + i]);
}

// ---------------- K1: hp = prev_h @ W_h2h + b_h2h ---------------------------
// grid (bg=32, nc=4): block = 8 rows x 128 cols; thread = 2 rows x 2 cols.
// Per-wave xs reads are wave-uniform broadcasts (rt = wave id).
__global__ __launch_bounds__(256) void hproj2_k(const float* __restrict__ ph,
                                                const float* __restrict__ Whh,
                                                const float* __restrict__ bh,
                                                float* __restrict__ hp) {
  __shared__ __align__(16) float xs[8][Hq];
  int bg = blockIdx.x >> 2;        // 0..31
  int nc = blockIdx.x & 3;         // 0..3
  int tid = threadIdx.x;
  for (int i = tid; i < 8 * Hq / 4; i += 256)
    ((float4*)&xs[0][0])[i] = ((const float4*)(ph + (size_t)bg * 8 * Hq))[i];
  __syncthreads();
  int rt = tid >> 6;               // wave id: rows {2rt, 2rt+1}
  int ct = tid & 63;               // cols n0 + 2*ct + {0,1}
  int n = nc * 128 + ct * 2;
  float a00 = 0, a01 = 0, a10 = 0, a11 = 0;
  for (int d = 0; d < Hq; d += 4) {
    float4 x0 = *(const float4*)&xs[rt * 2][d];
    float4 x1 = *(const float4*)&xs[rt * 2 + 1][d];
    #pragma unroll
    for (int j = 0; j < 4; j++) {
      float2 w = *(const float2*)&Whh[(size_t)(d + j) * Hq + n];
      float xj0 = ((const float*)&x0)[j];
      float xj1 = ((const float*)&x1)[j];
      a00 += xj0 * w.x; a01 += xj0 * w.y;
      a10 += xj1 * w.x; a11 += xj1 * w.y;
    }
  }
  float b0 = bh[n], b1 = bh[n + 1];
  int row = bg * 8 + rt * 2;
  hp[(size_t)row * Hq + n] = a00 + b0;
  hp[(size_t)row * Hq + n + 1] = a01 + b1;
  hp[(size_t)(row + 1) * Hq + n] = a10 + b0;
  hp[(size_t)(row + 1) * Hq + n + 1] = a11 + b1;
}

// ---------------- K2: fused proj GEMM + tanh + w_score dot -> e ------------
#define BM 128
#define BN 128
#define BK 32
#define LDK 40  // shorts per LDS row: 32 + 8 pad

__global__ __launch_bounds__(256) void fused_score_k(
    const float* __restrict__ A,            // batch_H [65536, 512]
    const unsigned short* __restrict__ Wt,  // bf16 [N=512][K=512]
    const float* __restrict__ hp,           // [B, H]
    const float* __restrict__ wsc,          // [H]
    float* __restrict__ e) {                // [B*T], pre-zeroed
  __shared__ unsigned short As[BM * LDK];
  __shared__ unsigned short Bs[BN * LDK];
  __shared__ float hps[BN];
  __shared__ float wss[BN];

  const int tid = threadIdx.x;
  const int m0 = blockIdx.x * BM;
  const int n0 = blockIdx.y * BN;
  const int bb = m0 >> 8;  // batch idx, uniform per block (128 | 256)

  if (tid < BN) {
    hps[tid] = hp[(size_t)bb * Hq + n0 + tid];
    wss[tid] = wsc[n0 + tid];
  }

  const int wave = tid >> 6;
  const int lane = tid & 63;
  const int quad = lane >> 4;
  const int l16 = lane & 15;
  const int wm = (wave & 1) * 64;
  const int wn = (wave >> 1) * 64;

  f32x4 acc[4][4] = {};

  const int arow = tid >> 3;        // 0..31
  const int acol = (tid & 7) * 4;   // 0..28
  const int brow = tid >> 2;        // 0..63 (n), two passes of 64 rows
  const int bkh = (tid & 3) * 8;    // k offset in shorts: 0,8,16,24

  for (int k0 = 0; k0 < Hq; k0 += BK) {
    __syncthreads();
    // stage A: 128 rows x 32 k, fp32 -> bf16
    #pragma unroll
    for (int p = 0; p < 4; p++) {
      int r = arow + p * 32;
      const float4 v = *(const float4*)(&A[(size_t)(m0 + r) * Hq + k0 + acol]);
      ushort4 pk;
      pk.x = f2bf(v.x); pk.y = f2bf(v.y); pk.z = f2bf(v.z); pk.w = f2bf(v.w);
      *(ushort4*)&As[r * LDK + acol] = pk;
    }
    // stage B (already bf16-transposed): Bs[n][k]
    // uint4 = 8 shorts; 4 threads/row x 8 shorts = 32 shorts; 2 passes x 64 rows
    #pragma unroll
    for (int p = 0; p < 2; p++) {
      int r = brow + p * 64;
      const uint4 v = *(const uint4*)(&Wt[(size_t)(n0 + r) * Hq + k0 + bkh]);
      *(uint4*)&Bs[r * LDK + bkh] = v;
    }
    __syncthreads();

    short8 af[4], bfr[4];
    #pragma unroll
    for (int mi = 0; mi < 4; mi++)
      af[mi] = *(const short8*)&As[(wm + mi * 16 + l16) * LDK + quad * 8];
    #pragma unroll
    for (int ni = 0; ni < 4; ni++)
      bfr[ni] = *(const short8*)&Bs[(wn + ni * 16 + l16) * LDK + quad * 8];
    #pragma unroll
    for (int mi = 0; mi < 4; mi++)
      #pragma unroll
      for (int ni = 0; ni < 4; ni++)
        acc[mi][ni] = __builtin_amdgcn_mfma_f32_16x16x32_bf16(
            af[mi], bfr[ni], acc[mi][ni], 0, 0, 0);
  }

  // epilogue: e[m] += sum_n tanh(C[m,n] + hp[b,n]) * w_score[n]
  float hv[4], wv[4];
  #pragma unroll
  for (int ni = 0; ni < 4; ni++) {
    int c = wn + ni * 16 + l16;
    hv[ni] = hps[c];
    wv[ni] = wss[c];
  }
  #pragma unroll
  for (int mi = 0; mi < 4; mi++) {
    float s[4] = {0, 0, 0, 0};
    #pragma unroll
    for (int ni = 0; ni < 4; ni++)
      #pragma unroll
      for (int r = 0; r < 4; r++)
        s[r] += sat_tanh(acc[mi][ni][r] + hv[ni]) * wv[ni];
    #pragma unroll
    for (int r = 0; r < 4; r++) {
      s[r] += __shfl_xor(s[r], 8, 64);
      s[r] += __shfl_xor(s[r], 4, 64);
      s[r] += __shfl_xor(s[r], 2, 64);
      s[r] += __shfl_xor(s[r], 1, 64);
    }
    if (l16 == 0) {
      int row = m0 + wm + mi * 16 + quad * 4;
      #pragma unroll
      for (int r = 0; r < 4; r++) atomicAdd(&e[row + r], s[r]);
    }
  }
}

// ---------------- K3: softmax over T per batch, IN PLACE -------------------
__global__ __launch_bounds__(256) void softmax_k(float* __restrict__ ea) {
  __shared__ float red[8];
  int b = blockIdx.x, t = threadIdx.x;
  int wave = t >> 6, lane = t & 63;
  float x = ea[b * Tq + t];
  float m = x;
  #pragma unroll
  for (int off = 32; off >= 1; off >>= 1) m = fmaxf(m, __shfl_xor(m, off, 64));
  if (lane == 0) red[wave] = m;
  __syncthreads();
  m = fmaxf(fmaxf(red[0], red[1]), fmaxf(red[2], red[3]));
  float ex = __builtin_exp2f((x - m) * 1.442695041f);
  float s = ex;
  #pragma unroll
  for (int off = 32; off >= 1; off >>= 1) s += __shfl_xor(s, off, 64);
  if (lane == 0) red[4 + wave] = s;
  __syncthreads();
  s = red[4] + red[5] + red[6] + red[7];
  ea[b * Tq + t] = ex / s;
}

// ---------------- K4: context = alpha^T . batch_H --------------------------
__global__ __launch_bounds__(256) void context_k(const float* __restrict__ alpha,
                                                 const float* __restrict__ bH,
                                                 float* __restrict__ ctx) {
  __shared__ float al[Tq];
  int b = blockIdx.x, tid = threadIdx.x;
  al[tid] = alpha[b * Tq + tid];
  __syncthreads();
  const float2* Hp = (const float2*)(bH + (size_t)b * Tq * Hq);
  float ax = 0.f, ay = 0.f;
  #pragma unroll 4
  for (int t = 0; t < Tq; t++) {
    float a = al[t];
    float2 v = Hp[t * (Hq / 2) + tid];
    ax += a * v.x;
    ay += a * v.y;
  }
  float2 o; o.x = ax; o.y = ay;
  ((float2*)(ctx + (size_t)b * Hq))[tid] = o;
}

// ---------------- K5: z-GEMM + LSTM gates, high-occupancy ------------------
// grid (bg=32, hc=8): block = 8 rows x 64 h x 4 gates (256 n-cols of 2048).
// thread: rt = tid>>6 (wave id) -> rows {2rt, 2rt+1};
//         ct = tid&63 -> cols c = 4ct..4ct+3, c=(gate<<6)|ho, n = gate*512+hc*64+ho.
// Per 4-d: 4 coalesced float4 W loads + 2 wave-uniform ds_read_b128 + 32 FMA.
#define KXc 1120
__global__ __launch_bounds__(256) void zgates2_k(
    const float* __restrict__ ctx, const float* __restrict__ oneh,
    const float* __restrict__ ph, const float* __restrict__ pc,
    const float* __restrict__ Wl, const float* __restrict__ Ul,
    const float* __restrict__ bl,
    float* __restrict__ outh, float* __restrict__ outc) {
  __shared__ __align__(16) float xs[8 * KXc];  // 35.8 KB; reused for gate regroup
  const int bg = blockIdx.x >> 3;  // 0..31 (8 rows each)
  const int hc = blockIdx.x & 7;   // 0..7  (64 h each)
  const int tid = threadIdx.x;
  const int row0 = bg * 8;

  // stage X = [ctx(512) | oneh(96) | ph(512)] for 8 rows, packed per-row 1120
  for (int i = tid; i < 8 * 128; i += 256) {  // ctx: 8 rows x 128 float4
    int r = i >> 7, dd = (i & 127) * 4;
    *(float4*)&xs[r * KXc + dd] = *(const float4*)&ctx[(size_t)(row0 + r) * Hq + dd];
  }
  for (int i = tid; i < 8 * 128; i += 256) {  // ph -> offset 608
    int r = i >> 7, dd = (i & 127) * 4;
    *(float4*)&xs[r * KXc + 608 + dd] = *(const float4*)&ph[(size_t)(row0 + r) * Hq + dd];
  }
  if (tid < 8 * 24) {                          // oneh: 8 rows x 24 float4 -> offset 512
    int r = tid / 24, dd = (tid % 24) * 4;
    *(float4*)&xs[r * KXc + 512 + dd] = *(const float4*)&oneh[(row0 + r) * Eq + dd];
  }
  __syncthreads();

  const int rt = tid >> 6;           // wave id; rows {2rt, 2rt+1} (wave-uniform)
  const int ct = tid & 63;
  const int c0 = ct * 4;             // col in [0,256): (gate<<6)|ho
  const int gate = c0 >> 6;
  const int ho = c0 & 63;
  const int n = gate * 512 + hc * 64 + ho;  // col in W (4 consecutive)

  float acc0[4] = {0, 0, 0, 0};      // row 2rt
  float acc1[4] = {0, 0, 0, 0};      // row 2rt+1
  const float* xr0 = &xs[(rt * 2) * KXc];
  const float* xr1 = &xs[(rt * 2 + 1) * KXc];

  // d in [0,608): W_lstm rows
  for (int d = 0; d < 608; d += 4) {
    float4 x0 = *(const float4*)&xr0[d];
    float4 x1 = *(const float4*)&xr1[d];
    #pragma unroll
    for (int j = 0; j < 4; j++) {
      float4 w = *(const float4*)&Wl[(size_t)(d + j) * 2048 + n];
      float a = ((const float*)&x0)[j], b = ((const float*)&x1)[j];
      acc0[0] += a * w.x; acc0[1] += a * w.y; acc0[2] += a * w.z; acc0[3] += a * w.w;
      acc1[0] += b * w.x; acc1[1] += b * w.y; acc1[2] += b * w.z; acc1[3] += b * w.w;
    }
  }
  // d in [608,1120): U_lstm rows
  for (int d = 0; d < 512; d += 4) {
    float4 x0 = *(const float4*)&xr0[608 + d];
    float4 x1 = *(const float4*)&xr1[608 + d];
    #pragma unroll
    for (int j = 0; j < 4; j++) {
      float4 w = *(const float4*)&Ul[(size_t)(d + j) * 2048 + n];
      float a = ((const float*)&x0)[j], b = ((const float*)&x1)[j];
      acc0[0] += a * w.x; acc0[1] += a * w.y; acc0[2] += a * w.z; acc0[3] += a * w.w;
      acc1[0] += b * w.x; acc1[1] += b * w.y; acc1[2] += b * w.z; acc1[3] += b * w.w;
    }
  }

  // regroup gates via LDS: zs[r][c], r in [0,8), c in [0,256)
  __syncthreads();  // xs reads done in all waves
  float* zs = xs;
  #pragma unroll
  for (int j = 0; j < 4; j++) {
    zs[(rt * 2) * 256 + c0 + j] = acc0[j];
    zs[(rt * 2 + 1) * 256 + c0 + j] = acc1[j];
  }
  __syncthreads();

  // 512 (row,ho) pairs; each thread does 2
  #pragma unroll
  for (int p = tid; p < 512; p += 256) {
    int r = p >> 6, o = p & 63;
    int h = hc * 64 + o;
    int grow = row0 + r;
    float gi = zs[r * 256 + o]       + bl[h];
    float gf = zs[r * 256 + 64 + o]  + bl[512 + h];
    float gg = zs[r * 256 + 128 + o] + bl[1024 + h];
    float go = zs[r * 256 + 192 + o] + bl[1536 + h];
    float cn = sat_sig(gf) * pc[(size_t)grow * Hq + h] + sat_sig(gi) * sat_tanh(gg);
    float hn = sat_sig(go) * sat_tanh(cn);
    outh[(size_t)grow * Hq + h] = hn;
    outc[(size_t)grow * Hq + h] = cn;
  }
}

extern "C" void kernel_launch(void* const* d_in, const int* in_sizes, int n_in,
                              void* d_out, int out_size, void* d_ws, size_t ws_size,
                              hipStream_t stream) {
  const float* prev_h = (const float*)d_in[0];
  const float* prev_c = (const float*)d_in[1];
  const float* batch_H = (const float*)d_in[2];
  const float* oneh = (const float*)d_in[3];
  const float* W_i2h = (const float*)d_in[4];
  const float* W_h2h = (const float*)d_in[5];
  const float* b_h2h = (const float*)d_in[6];
  const float* w_score = (const float*)d_in[7];
  const float* W_lstm = (const float*)d_in[8];
  const float* U_lstm = (const float*)d_in[9];
  const float* b_lstm = (const float*)d_in[10];

  float* out = (float*)d_out;
  float* outh = out;                 // [B,H]
  float* outc = out + Bq * Hq;       // [B,H]
  float* alpha = out + 2 * Bq * Hq;  // [B,T] — doubles as e scratch

  // ws layout (1.0 MB): [hp | later overlaid by ctx][Wt bf16]
  float* ws = (float*)d_ws;
  float* hp = ws;                                        // 131072 f
  float* ctx = ws;                                       // overlays hp (hp dead after K2)
  unsigned short* Wt = (unsigned short*)(ws + 131072);   // 262144 shorts = 512 KB

  hipMemsetAsync(alpha, 0, Bq * Tq * sizeof(float), stream);
  convW_k<<<256, 256, 0, stream>>>(W_i2h, Wt);
  hproj2_k<<<128, 256, 0, stream>>>(prev_h, W_h2h, b_h2h, hp);
  dim3 g2(512, 4);
  fused_score_k<<<g2, 256, 0, stream>>>(batch_H, Wt, hp, w_score, alpha);
  softmax_k<<<256, 256, 0, stream>>>(alpha);
  context_k<<<256, 256, 0, stream>>>(alpha, batch_H, ctx);
  zgates2_k<<<256, 256, 0, stream>>>(ctx, oneh, prev_h, prev_c,
                                     W_lstm, U_lstm, b_lstm, outh, outc);
}

// Round 5
// 399.117 us; speedup vs baseline: 1.6510x; 1.2177x over previous
//
#include <hip/hip_runtime.h>
#include <hip/hip_bf16.h>
#include <math.h>

#define Bq 256
#define Tq 256
#define Hq 512
#define Eq 96

typedef __attribute__((ext_vector_type(8))) short short8;
typedef __attribute__((ext_vector_type(4))) float f32x4;

static __device__ __forceinline__ unsigned short f2bf(float f) {
  union { float f; unsigned u; } v; v.f = f;
  unsigned r = v.u + 0x7FFF + ((v.u >> 16) & 1);
  return (unsigned short)(r >> 16);
}

static __device__ __forceinline__ float sat_tanh(float x) {
  float ax = fminf(fabsf(x), 15.0f);
  float e = __builtin_exp2f(ax * 2.885390082f);
  float t = 1.0f - 2.0f / (e + 1.0f);
  return copysignf(t, x);
}

static __device__ __forceinline__ float sat_sig(float x) {
  float cx = fmaxf(fminf(x, 30.0f), -30.0f);
  return 1.0f / (1.0f + __builtin_exp2f(-cx * 1.442695041f));
}

// ---------------- K0: W_i2h fp32 [K][N] -> bf16 transposed [N][K] ----------
__global__ __launch_bounds__(256) void convW_k(const float* __restrict__ W,
                                               unsigned short* __restrict__ Wt) {
  __shared__ float tile[32][33];
  int bx = blockIdx.x & 15, by = blockIdx.x >> 4;
  int tx = threadIdx.x & 31, ty = threadIdx.x >> 5;
  #pragma unroll
  for (int i = 0; i < 32; i += 8)
    tile[ty + i][tx] = W[(size_t)(by * 32 + ty + i) * Hq + bx * 32 + tx];
  __syncthreads();
  #pragma unroll
  for (int i = 0; i < 32; i += 8)
    Wt[(size_t)(bx * 32 + ty + i) * Hq + by * 32 + tx] = f2bf(tile[tx][ty + i]);
}

// ---------------- K1: hp partial GEMM, K-split, atomicAdd ------------------
// grid 512: bg(32) x nc(4) x ks(4). Block: 8 rows x 128 cols x 128 k.
// hp must be pre-zeroed; bias b_h2h folded into fused_score.
__global__ __launch_bounds__(256) void hsplit_k(const float* __restrict__ ph,
                                                const float* __restrict__ Whh,
                                                float* __restrict__ hp) {
  __shared__ __align__(16) float xs[8][128];
  const int ks = blockIdx.x & 3;
  const int nc = (blockIdx.x >> 2) & 3;
  const int bg = blockIdx.x >> 4;
  const int tid = threadIdx.x;
  const int row0 = bg * 8;
  const int d0 = ks * 128;
  for (int i = tid; i < 8 * 32; i += 256) {
    int r = i >> 5, dd = (i & 31) * 4;
    *(float4*)&xs[r][dd] = *(const float4*)&ph[(size_t)(row0 + r) * Hq + d0 + dd];
  }
  __syncthreads();
  const int rt = tid >> 6;
  const int ct = tid & 63;
  const int n = nc * 128 + ct * 2;
  float a00 = 0, a01 = 0, a10 = 0, a11 = 0;
  for (int dd = 0; dd < 128; dd += 4) {
    float4 x0 = *(const float4*)&xs[rt * 2][dd];
    float4 x1 = *(const float4*)&xs[rt * 2 + 1][dd];
    #pragma unroll
    for (int j = 0; j < 4; j++) {
      float2 w = *(const float2*)&Whh[(size_t)(d0 + dd + j) * Hq + n];
      float xj0 = ((const float*)&x0)[j];
      float xj1 = ((const float*)&x1)[j];
      a00 += xj0 * w.x; a01 += xj0 * w.y;
      a10 += xj1 * w.x; a11 += xj1 * w.y;
    }
  }
  int row = row0 + rt * 2;
  atomicAdd(&hp[(size_t)row * Hq + n], a00);
  atomicAdd(&hp[(size_t)row * Hq + n + 1], a01);
  atomicAdd(&hp[(size_t)(row + 1) * Hq + n], a10);
  atomicAdd(&hp[(size_t)(row + 1) * Hq + n + 1], a11);
}

// ---------------- K2: fused proj GEMM + tanh + w_score dot -> e ------------
#define BM 128
#define BN 128
#define BK 32
#define LDK 40

__global__ __launch_bounds__(256) void fused_score_k(
    const float* __restrict__ A,
    const unsigned short* __restrict__ Wt,
    const float* __restrict__ hp,
    const float* __restrict__ bh,
    const float* __restrict__ wsc,
    float* __restrict__ e) {
  __shared__ unsigned short As[BM * LDK];
  __shared__ unsigned short Bs[BN * LDK];
  __shared__ float hps[BN];
  __shared__ float wss[BN];

  const int tid = threadIdx.x;
  const int m0 = blockIdx.x * BM;
  const int n0 = blockIdx.y * BN;
  const int bb = m0 >> 8;

  if (tid < BN) {
    hps[tid] = hp[(size_t)bb * Hq + n0 + tid] + bh[n0 + tid];
    wss[tid] = wsc[n0 + tid];
  }

  const int wave = tid >> 6;
  const int lane = tid & 63;
  const int quad = lane >> 4;
  const int l16 = lane & 15;
  const int wm = (wave & 1) * 64;
  const int wn = (wave >> 1) * 64;

  f32x4 acc[4][4] = {};

  const int arow = tid >> 3;
  const int acol = (tid & 7) * 4;
  const int brow = tid >> 2;
  const int bkh = (tid & 3) * 8;

  for (int k0 = 0; k0 < Hq; k0 += BK) {
    __syncthreads();
    #pragma unroll
    for (int p = 0; p < 4; p++) {
      int r = arow + p * 32;
      const float4 v = *(const float4*)(&A[(size_t)(m0 + r) * Hq + k0 + acol]);
      ushort4 pk;
      pk.x = f2bf(v.x); pk.y = f2bf(v.y); pk.z = f2bf(v.z); pk.w = f2bf(v.w);
      *(ushort4*)&As[r * LDK + acol] = pk;
    }
    #pragma unroll
    for (int p = 0; p < 2; p++) {
      int r = brow + p * 64;
      const uint4 v = *(const uint4*)(&Wt[(size_t)(n0 + r) * Hq + k0 + bkh]);
      *(uint4*)&Bs[r * LDK + bkh] = v;
    }
    __syncthreads();

    short8 af[4], bfr[4];
    #pragma unroll
    for (int mi = 0; mi < 4; mi++)
      af[mi] = *(const short8*)&As[(wm + mi * 16 + l16) * LDK + quad * 8];
    #pragma unroll
    for (int ni = 0; ni < 4; ni++)
      bfr[ni] = *(const short8*)&Bs[(wn + ni * 16 + l16) * LDK + quad * 8];
    #pragma unroll
    for (int mi = 0; mi < 4; mi++)
      #pragma unroll
      for (int ni = 0; ni < 4; ni++)
        acc[mi][ni] = __builtin_amdgcn_mfma_f32_16x16x32_bf16(
            af[mi], bfr[ni], acc[mi][ni], 0, 0, 0);
  }

  float hv[4], wv[4];
  #pragma unroll
  for (int ni = 0; ni < 4; ni++) {
    int c = wn + ni * 16 + l16;
    hv[ni] = hps[c];
    wv[ni] = wss[c];
  }
  #pragma unroll
  for (int mi = 0; mi < 4; mi++) {
    float s[4] = {0, 0, 0, 0};
    #pragma unroll
    for (int ni = 0; ni < 4; ni++)
      #pragma unroll
      for (int r = 0; r < 4; r++)
        s[r] += sat_tanh(acc[mi][ni][r] + hv[ni]) * wv[ni];
    #pragma unroll
    for (int r = 0; r < 4; r++) {
      s[r] += __shfl_xor(s[r], 8, 64);
      s[r] += __shfl_xor(s[r], 4, 64);
      s[r] += __shfl_xor(s[r], 2, 64);
      s[r] += __shfl_xor(s[r], 1, 64);
    }
    if (l16 == 0) {
      int row = m0 + wm + mi * 16 + quad * 4;
      #pragma unroll
      for (int r = 0; r < 4; r++) atomicAdd(&e[row + r], s[r]);
    }
  }
}

// ---------------- K3: softmax over T per batch, IN PLACE -------------------
__global__ __launch_bounds__(256) void softmax_k(float* __restrict__ ea) {
  __shared__ float red[8];
  int b = blockIdx.x, t = threadIdx.x;
  int wave = t >> 6, lane = t & 63;
  float x = ea[b * Tq + t];
  float m = x;
  #pragma unroll
  for (int off = 32; off >= 1; off >>= 1) m = fmaxf(m, __shfl_xor(m, off, 64));
  if (lane == 0) red[wave] = m;
  __syncthreads();
  m = fmaxf(fmaxf(red[0], red[1]), fmaxf(red[2], red[3]));
  float ex = __builtin_exp2f((x - m) * 1.442695041f);
  float s = ex;
  #pragma unroll
  for (int off = 32; off >= 1; off >>= 1) s += __shfl_xor(s, off, 64);
  if (lane == 0) red[4 + wave] = s;
  __syncthreads();
  s = red[4] + red[5] + red[6] + red[7];
  ea[b * Tq + t] = ex / s;
}

// ---------------- K4: context partials, T-split, atomicAdd -----------------
// grid 1024: b(256) x tc(4). Block: 64 t-rows, 512 h. ctx pre-zeroed.
__global__ __launch_bounds__(256) void ctxsplit_k(const float* __restrict__ alpha,
                                                  const float* __restrict__ bH,
                                                  float* __restrict__ ctx) {
  __shared__ float al[64];
  const int b = blockIdx.x >> 2;
  const int tc = blockIdx.x & 3;
  const int tid = threadIdx.x;
  if (tid < 64) al[tid] = alpha[b * Tq + tc * 64 + tid];
  __syncthreads();
  const float2* Hp = (const float2*)(bH + (size_t)b * Tq * Hq + (size_t)tc * 64 * Hq);
  float ax = 0.f, ay = 0.f;
  #pragma unroll 8
  for (int t = 0; t < 64; t++) {
    float a = al[t];
    float2 v = Hp[t * (Hq / 2) + tid];
    ax += a * v.x;
    ay += a * v.y;
  }
  atomicAdd(&ctx[(size_t)b * Hq + 2 * tid], ax);
  atomicAdd(&ctx[(size_t)b * Hq + 2 * tid + 1], ay);
}

// ---------------- K5a: z partial GEMM, K-split, atomicAdd ------------------
// grid 1024: bg(32) x hc(8) x ks(4). Block: 8 rows x 256 cols x 280 k.
// z[256][2048] pre-zeroed. x = [ctx(512)|oneh(96)|ph(512)].
__global__ __launch_bounds__(256) void zsplit_k(
    const float* __restrict__ ctx, const float* __restrict__ oneh,
    const float* __restrict__ ph, const float* __restrict__ Wl,
    const float* __restrict__ Ul, float* __restrict__ z) {
  __shared__ __align__(16) float xs[8 * 280];
  const int ks = blockIdx.x & 3;
  const int hc = (blockIdx.x >> 2) & 7;
  const int bg = blockIdx.x >> 5;
  const int tid = threadIdx.x;
  const int row0 = bg * 8;
  const int dbase = ks * 280;

  for (int i = tid; i < 8 * 280; i += 256) {
    int r = i / 280, dd = i % 280;
    int g = dbase + dd;
    float v;
    if (g < 512) v = ctx[(size_t)(row0 + r) * Hq + g];
    else if (g < 608) v = oneh[(row0 + r) * Eq + (g - 512)];
    else v = ph[(size_t)(row0 + r) * Hq + (g - 608)];
    xs[r * 280 + dd] = v;
  }
  __syncthreads();

  const int rt = tid >> 6;
  const int ct = tid & 63;
  const int c0 = ct * 4;
  const int gate = c0 >> 6;
  const int ho = c0 & 63;
  const int n = gate * 512 + hc * 64 + ho;

  float acc0[4] = {0, 0, 0, 0};
  float acc1[4] = {0, 0, 0, 0};
  const float* xr0 = &xs[(rt * 2) * 280];
  const float* xr1 = &xs[(rt * 2 + 1) * 280];

  for (int dd = 0; dd < 280; dd += 4) {
    float4 x0 = *(const float4*)&xr0[dd];
    float4 x1 = *(const float4*)&xr1[dd];
    #pragma unroll
    for (int j = 0; j < 4; j++) {
      int d = dbase + dd + j;
      const float* wp = (d < 608) ? &Wl[(size_t)d * 2048 + n]
                                  : &Ul[(size_t)(d - 608) * 2048 + n];
      float4 w = *(const float4*)wp;
      float a = ((const float*)&x0)[j], b = ((const float*)&x1)[j];
      acc0[0] += a * w.x; acc0[1] += a * w.y; acc0[2] += a * w.z; acc0[3] += a * w.w;
      acc1[0] += b * w.x; acc1[1] += b * w.y; acc1[2] += b * w.z; acc1[3] += b * w.w;
    }
  }
  const int r0 = row0 + rt * 2;
  #pragma unroll
  for (int j = 0; j < 4; j++) {
    atomicAdd(&z[(size_t)r0 * 2048 + n + j], acc0[j]);
    atomicAdd(&z[(size_t)(r0 + 1) * 2048 + n + j], acc1[j]);
  }
}

// ---------------- K5b: gates from z ----------------------------------------
__global__ __launch_bounds__(256) void gatesz_k(const float* __restrict__ z,
                                                const float* __restrict__ bl,
                                                const float* __restrict__ pc,
                                                float* __restrict__ outh,
                                                float* __restrict__ outc) {
  int p = blockIdx.x * 256 + threadIdx.x;  // 0..65535
  #pragma unroll
  for (int q = 0; q < 2; q++, p += 65536) {
    int r = p >> 9, h = p & 511;
    const float* zb = z + (size_t)r * 2048;
    float gi = zb[h] + bl[h];
    float gf = zb[512 + h] + bl[512 + h];
    float gg = zb[1024 + h] + bl[1024 + h];
    float go = zb[1536 + h] + bl[1536 + h];
    float cn = sat_sig(gf) * pc[p] + sat_sig(gi) * sat_tanh(gg);
    float hn = sat_sig(go) * sat_tanh(cn);
    outh[p] = hn;
    outc[p] = cn;
  }
}

// ---------------- fallback K5 (ws too small for z): fused z-GEMM+gates -----
#define KXc 1120
__global__ __launch_bounds__(256) void zgates2_k(
    const float* __restrict__ ctx, const float* __restrict__ oneh,
    const float* __restrict__ ph, const float* __restrict__ pc,
    const float* __restrict__ Wl, const float* __restrict__ Ul,
    const float* __restrict__ bl,
    float* __restrict__ outh, float* __restrict__ outc) {
  __shared__ __align__(16) float xs[8 * KXc];
  const int bg = blockIdx.x >> 3;
  const int hc = blockIdx.x & 7;
  const int tid = threadIdx.x;
  const int row0 = bg * 8;

  for (int i = tid; i < 8 * 128; i += 256) {
    int r = i >> 7, dd = (i & 127) * 4;
    *(float4*)&xs[r * KXc + dd] = *(const float4*)&ctx[(size_t)(row0 + r) * Hq + dd];
  }
  for (int i = tid; i < 8 * 128; i += 256) {
    int r = i >> 7, dd = (i & 127) * 4;
    *(float4*)&xs[r * KXc + 608 + dd] = *(const float4*)&ph[(size_t)(row0 + r) * Hq + dd];
  }
  if (tid < 8 * 24) {
    int r = tid / 24, dd = (tid % 24) * 4;
    *(float4*)&xs[r * KXc + 512 + dd] = *(const float4*)&oneh[(row0 + r) * Eq + dd];
  }
  __syncthreads();

  const int rt = tid >> 6;
  const int ct = tid & 63;
  const int c0 = ct * 4;
  const int gate = c0 >> 6;
  const int ho = c0 & 63;
  const int n = gate * 512 + hc * 64 + ho;

  float acc0[4] = {0, 0, 0, 0};
  float acc1[4] = {0, 0, 0, 0};
  const float* xr0 = &xs[(rt * 2) * KXc];
  const float* xr1 = &xs[(rt * 2 + 1) * KXc];

  for (int d = 0; d < 608; d += 4) {
    float4 x0 = *(const float4*)&xr0[d];
    float4 x1 = *(const float4*)&xr1[d];
    #pragma unroll
    for (int j = 0; j < 4; j++) {
      float4 w = *(const float4*)&Wl[(size_t)(d + j) * 2048 + n];
      float a = ((const float*)&x0)[j], b = ((const float*)&x1)[j];
      acc0[0] += a * w.x; acc0[1] += a * w.y; acc0[2] += a * w.z; acc0[3] += a * w.w;
      acc1[0] += b * w.x; acc1[1] += b * w.y; acc1[2] += b * w.z; acc1[3] += b * w.w;
    }
  }
  for (int d = 0; d < 512; d += 4) {
    float4 x0 = *(const float4*)&xr0[608 + d];
    float4 x1 = *(const float4*)&xr1[608 + d];
    #pragma unroll
    for (int j = 0; j < 4; j++) {
      float4 w = *(const float4*)&Ul[(size_t)(d + j) * 2048 + n];
      float a = ((const float*)&x0)[j], b = ((const float*)&x1)[j];
      acc0[0] += a * w.x; acc0[1] += a * w.y; acc0[2] += a * w.z; acc0[3] += a * w.w;
      acc1[0] += b * w.x; acc1[1] += b * w.y; acc1[2] += b * w.z; acc1[3] += b * w.w;
    }
  }

  __syncthreads();
  float* zs = xs;
  #pragma unroll
  for (int j = 0; j < 4; j++) {
    zs[(rt * 2) * 256 + c0 + j] = acc0[j];
    zs[(rt * 2 + 1) * 256 + c0 + j] = acc1[j];
  }
  __syncthreads();

  #pragma unroll
  for (int p = tid; p < 512; p += 256) {
    int r = p >> 6, o = p & 63;
    int h = hc * 64 + o;
    int grow = row0 + r;
    float gi = zs[r * 256 + o]       + bl[h];
    float gf = zs[r * 256 + 64 + o]  + bl[512 + h];
    float gg = zs[r * 256 + 128 + o] + bl[1024 + h];
    float go = zs[r * 256 + 192 + o] + bl[1536 + h];
    float cn = sat_sig(gf) * pc[(size_t)grow * Hq + h] + sat_sig(gi) * sat_tanh(gg);
    float hn = sat_sig(go) * sat_tanh(cn);
    outh[(size_t)grow * Hq + h] = hn;
    outc[(size_t)grow * Hq + h] = cn;
  }
}

extern "C" void kernel_launch(void* const* d_in, const int* in_sizes, int n_in,
                              void* d_out, int out_size, void* d_ws, size_t ws_size,
                              hipStream_t stream) {
  const float* prev_h = (const float*)d_in[0];
  const float* prev_c = (const float*)d_in[1];
  const float* batch_H = (const float*)d_in[2];
  const float* oneh = (const float*)d_in[3];
  const float* W_i2h = (const float*)d_in[4];
  const float* W_h2h = (const float*)d_in[5];
  const float* b_h2h = (const float*)d_in[6];
  const float* w_score = (const float*)d_in[7];
  const float* W_lstm = (const float*)d_in[8];
  const float* U_lstm = (const float*)d_in[9];
  const float* b_lstm = (const float*)d_in[10];

  float* out = (float*)d_out;
  float* outh = out;
  float* outc = out + Bq * Hq;
  float* alpha = out + 2 * Bq * Hq;

  // ws layout: [0,512K) hp -> ctx; [512K,1M) Wt; z (2MB) overlays [512K,2.5M)
  float* ws = (float*)d_ws;
  float* hp = ws;
  float* ctx = ws;
  unsigned short* Wt = (unsigned short*)(ws + 131072);
  float* z = ws + 131072;  // 524288 floats, overlays Wt (dead by then)

  const bool bigws = ws_size >= 2621440;  // 2.5 MB needed for z path

  hipMemsetAsync(alpha, 0, Bq * Tq * sizeof(float), stream);
  hipMemsetAsync(hp, 0, Bq * Hq * sizeof(float), stream);
  convW_k<<<256, 256, 0, stream>>>(W_i2h, Wt);
  hsplit_k<<<512, 256, 0, stream>>>(prev_h, W_h2h, hp);
  dim3 g2(512, 4);
  fused_score_k<<<g2, 256, 0, stream>>>(batch_H, Wt, hp, b_h2h, w_score, alpha);
  softmax_k<<<256, 256, 0, stream>>>(alpha);
  if (bigws) {
    // zero ctx (512K) + z (2M) in one contiguous memset; Wt/hp dead now
    hipMemsetAsync(ws, 0, 2621440, stream);
    ctxsplit_k<<<1024, 256, 0, stream>>>(alpha, batch_H, ctx);
    zsplit_k<<<1024, 256, 0, stream>>>(ctx, oneh, prev_h, W_lstm, U_lstm, z);
    gatesz_k<<<256, 256, 0, stream>>>(z, b_lstm, prev_c, outh, outc);
  } else {
    hipMemsetAsync(ctx, 0, Bq * Hq * sizeof(float), stream);
    ctxsplit_k<<<1024, 256, 0, stream>>>(alpha, batch_H, ctx);
    zgates2_k<<<256, 256, 0, stream>>>(ctx, oneh, prev_h, prev_c,
                                       W_lstm, U_lstm, b_lstm, outh, outc);
  }
}